// Round 7
// baseline (234.418 us; speedup 1.0000x reference)
//
#include <hip/hip_runtime.h>

#define S_DIM 512
#define H_DIM 512
#define NH 256
#define TI 16
#define TJ 8
#define SROW 520   // 512 + 8-half pad: rotates banks per row; legal (per-row DMA base)

#define AS1 __attribute__((address_space(1)))
#define AS3 __attribute__((address_space(3)))

typedef _Float16 half8 __attribute__((ext_vector_type(8)));
typedef float f32x16 __attribute__((ext_vector_type(16)));

// ---------------- k0: W2 [512,256] fp32 -> fragment-major f16 w2L ----------------
__global__ __launch_bounds__(256) void convert_w2_kernel(const float* __restrict__ W2,
                                                         _Float16* __restrict__ w2L) {
    int t = blockIdx.x * 256 + threadIdx.x;   // 16384
    int gcb = t >> 8, n = t & 255;
    half8 v;
#pragma unroll
    for (int j = 0; j < 8; j++) v[j] = (_Float16)W2[(size_t)(gcb * 8 + j) * NH + n];
    *(half8*)&w2L[((size_t)gcb * 256 + n) * 8] = v;
}

// ---------------- k1: prep GEMM, fp32 in (inline cvt), f16 out --------------------
// [1024x512] @ [512x1024]; grid (16,32), block 128 = 2 waves, wave tile 32M x 32N.
__global__ __launch_bounds__(128) void prep_mfma_kernel(const float* __restrict__ feats,
        const float* __restrict__ W1, const float* __restrict__ b1,
        _Float16* __restrict__ aH, _Float16* __restrict__ cH) {
    const int tid = threadIdx.x, wave = tid >> 6, lane = tid & 63;
    const int m32 = lane & 31, ch = lane >> 5;
    const int m0 = blockIdx.y * 32;
    const int n = blockIdx.x * 64 + wave * 32 + m32;          // 0..1023
    const bool fh = (n < H_DIM);
    // Bw1[k][n] = n<512 ? W1[k][n] : W1[512+k][n-512]
    const float* wcol = fh ? &W1[n] : &W1[(size_t)H_DIM * H_DIM + (n - H_DIM)];
    const float* arow = &feats[(size_t)(m0 + m32) * H_DIM + ch * 8];

    f32x16 acc = (f32x16)0.f;
#pragma unroll
    for (int ks = 0; ks < 32; ks++) {
        const int kbase = ks * 16 + ch * 8;
        float4 a0 = *(const float4*)&arow[ks * 16];
        float4 a1 = *(const float4*)&arow[ks * 16 + 4];
        half8 af, bf;
        af[0] = (_Float16)a0.x; af[1] = (_Float16)a0.y;
        af[2] = (_Float16)a0.z; af[3] = (_Float16)a0.w;
        af[4] = (_Float16)a1.x; af[5] = (_Float16)a1.y;
        af[6] = (_Float16)a1.z; af[7] = (_Float16)a1.w;
#pragma unroll
        for (int j = 0; j < 8; j++) bf[j] = (_Float16)wcol[(size_t)(kbase + j) * H_DIM];
        acc = __builtin_amdgcn_mfma_f32_32x32x16_f16(af, bf, acc, 0, 0, 0);
    }
    const float bias = fh ? b1[n] : 0.f;
#pragma unroll
    for (int r = 0; r < 16; r++) {
        int m = m0 + (r & 3) + 8 * (r >> 2) + 4 * ch;
        float v = acc[r] + bias;
        if (fh) aH[(size_t)m * H_DIM + n] = (_Float16)v;
        else    cH[(size_t)m * H_DIM + (n - H_DIM)] = (_Float16)v;
    }
}

// ---------------- k2: pair GEMM, 32x32x16, mt=2 nt=2, dual depth-2 pipeline -------
// grid (64,32,B). block 512 = 8 waves = 2 mg x 4 ng. Wave = 64 pairs x 64 N.
// Block = 128 pairs (16i x 8j) x 256 N.
__global__ __launch_bounds__(512, 4) void pair_kernel(
        const _Float16* __restrict__ aH, const _Float16* __restrict__ cH,
        const _Float16* __restrict__ w2L,
        const float* __restrict__ b2, const float* __restrict__ W3,
        const float* __restrict__ b3, float* __restrict__ out) {
    const int jt = blockIdx.x, it = blockIdx.y, b = blockIdx.z;
    const int i0 = it * TI, j0 = jt * TJ;

    __shared__ __align__(16) _Float16 sa[TI * SROW];    // 16.25 KB
    __shared__ __align__(16) _Float16 sc[TJ * SROW];    //  8.1 KB
    __shared__ float spart[2 * 64 * 32];                // 16 KB [mg][row64][col32 rot]

    const int tid = threadIdx.x;
    const int wave = tid >> 6, lane = tid & 63;
    const int mg = wave >> 2, ng = wave & 3;
    const int nb = ng * 64;
    const int m32 = lane & 31, ch = lane >> 5;

    // ---- stage 16 a-rows + 8 c-rows (row base wave-uniform; pad between rows) ----
#pragma unroll
    for (int rr0 = 0; rr0 < 3; rr0++) {
        int rr = rr0 * 8 + wave;
        if (rr < TI) {
            __builtin_amdgcn_global_load_lds(
                (const AS1 unsigned int*)&aH[((size_t)(b * S_DIM + i0 + rr)) * H_DIM + lane * 8],
                (AS3 unsigned int*)&sa[rr * SROW], 16, 0, 0);
        } else {
            int cr = rr - TI;
            __builtin_amdgcn_global_load_lds(
                (const AS1 unsigned int*)&cH[((size_t)(b * S_DIM + j0 + cr)) * H_DIM + lane * 8],
                (AS3 unsigned int*)&sc[cr * SROW], 16, 0, 0);
        }
    }

    // pair row r_blk = mg*64 + mt*32 + m32 ; il = r_blk>>3, jl = r_blk&7
    const int il0 = mg * 8 + (m32 >> 3);        // mt=0
    const int il1 = il0 + 4;                    // mt=1
    const int jl = m32 & 7;
    const _Float16* vaB0 = &sa[il0 * SROW + ch * 8];
    const _Float16* vaB1 = &sa[il1 * SROW + ch * 8];
    const _Float16* vcB  = &sc[jl * SROW + ch * 8];

    f32x16 acc[2][2];
#pragma unroll
    for (int mt = 0; mt < 2; mt++)
#pragma unroll
        for (int nt = 0; nt < 2; nt++) acc[mt][nt] = (f32x16)0.f;

    // B fragment-major: chunk (kc, n) at (kc*256+n)*8 halves; kc = ks*2 + ch
    const _Float16* bp = &w2L[((size_t)ch * 256 + nb + m32) * 8];
    half8 bB[2][2];
    bB[0][0] = *(const half8*)&bp[0];
    bB[0][1] = *(const half8*)&bp[256];
    bB[1][0] = *(const half8*)&bp[4096];
    bB[1][1] = *(const half8*)&bp[4096 + 256];

    __syncthreads();   // sa/sc staged

    // LDS depth-2 register prefetch
    half8 aB[2][3];
    aB[0][0] = *(const half8*)&vaB0[0];
    aB[0][1] = *(const half8*)&vaB1[0];
    aB[0][2] = *(const half8*)&vcB[0];

#pragma unroll
    for (int ks = 0; ks < 32; ks++) {
        const int cur = ks & 1, nxt = cur ^ 1;
        // issue next-iteration LDS reads first (full-iteration waitcnt distance)
        if (ks < 31) {
            aB[nxt][0] = *(const half8*)&vaB0[(ks + 1) * 16];
            aB[nxt][1] = *(const half8*)&vaB1[(ks + 1) * 16];
            aB[nxt][2] = *(const half8*)&vcB[(ks + 1) * 16];
        }
        half8 bf0 = bB[cur][0], bf1 = bB[cur][1];
        if (ks < 30) {
            const _Float16* bn = bp + (size_t)(ks + 2) * 4096;
            bB[cur][0] = *(const half8*)&bn[0];
            bB[cur][1] = *(const half8*)&bn[256];
        }
        half8 af0 = __builtin_elementwise_max(aB[cur][0] + aB[cur][2], (half8)(_Float16)0.f);
        half8 af1 = __builtin_elementwise_max(aB[cur][1] + aB[cur][2], (half8)(_Float16)0.f);
        acc[0][0] = __builtin_amdgcn_mfma_f32_32x32x16_f16(af0, bf0, acc[0][0], 0, 0, 0);
        acc[0][1] = __builtin_amdgcn_mfma_f32_32x32x16_f16(af0, bf1, acc[0][1], 0, 0, 0);
        acc[1][0] = __builtin_amdgcn_mfma_f32_32x32x16_f16(af1, bf0, acc[1][0], 0, 0, 0);
        acc[1][1] = __builtin_amdgcn_mfma_f32_32x32x16_f16(af1, bf1, acc[1][1], 0, 0, 0);
    }

    // ---- fused epilogue: relu(acc+b2) . W3 over this wave's 64 N ----
    float b2v[2], w3v[2];
#pragma unroll
    for (int nt = 0; nt < 2; nt++) {
        int n = nb + nt * 32 + m32;
        b2v[nt] = b2[n];
        w3v[nt] = W3[n];
    }
#pragma unroll
    for (int mt = 0; mt < 2; mt++)
#pragma unroll
        for (int r = 0; r < 16; r++) {
            float s = 0.f;
#pragma unroll
            for (int nt = 0; nt < 2; nt++) {
                float v = acc[mt][nt][r] + b2v[nt];
                v = v > 0.f ? v : 0.f;
                s += v * w3v[nt];
            }
            // pre-reduce over 32 cols -> 8 col-groups (stays within ch-half)
            s += __shfl_xor(s, 8);
            s += __shfl_xor(s, 16);
            if (m32 < 8) {
                int row = mt * 32 + (r & 3) + 8 * (r >> 2) + 4 * ch;
                int col = ng * 8 + m32;
                spart[mg * 2048 + row * 32 + ((col + row) & 31)] = s;
            }
        }
    __syncthreads();
    {
        const int R = tid >> 2, sub = tid & 3;   // R = block pair row 0..127
        const int mgf = R >> 6, rowf = R & 63;
        const float* base = &spart[mgf * 2048 + rowf * 32];
        float s = 0.f;
#pragma unroll
        for (int k = 0; k < 8; k++) s += base[(sub * 8 + k + rowf) & 31];
        s += __shfl_xor(s, 1);
        s += __shfl_xor(s, 2);
        if (sub == 0) {
            float tot = s + b3[0];
            float sg = 1.f / (1.f + __expf(-tot));
            int i = i0 + (R >> 3), j = j0 + (R & 7);
            out[(size_t)b * S_DIM * S_DIM + (size_t)i * S_DIM + j] = sg;
        }
    }
}

extern "C" void kernel_launch(void* const* d_in, const int* in_sizes, int n_in,
                              void* d_out, int out_size, void* d_ws, size_t ws_size,
                              hipStream_t stream) {
    const float* feats = (const float*)d_in[0];
    const float* W1 = (const float*)d_in[1];
    const float* b1 = (const float*)d_in[2];
    const float* W2 = (const float*)d_in[3];
    const float* b2 = (const float*)d_in[4];
    const float* W3 = (const float*)d_in[5];
    const float* b3 = (const float*)d_in[6];
    float* out = (float*)d_out;

    const int B = in_sizes[0] / (S_DIM * H_DIM);   // = 2

    char* ws = (char*)d_ws;
    _Float16* aH   = (_Float16*)ws;                 // 1 MB
    _Float16* cH   = (_Float16*)(ws + (1 << 20));   // 1 MB
    _Float16* w2L  = (_Float16*)(ws + (2 << 20));   // 256 KB

    convert_w2_kernel<<<64, 256, 0, stream>>>(W2, w2L);
    prep_mfma_kernel<<<dim3(16, 32), 128, 0, stream>>>(feats, W1, b1, aH, cH);
    pair_kernel<<<dim3(S_DIM / TJ, S_DIM / TI, B), 512, 0, stream>>>(aH, cH, w2L, b2, W3, b3, out);
}